// Round 6
// baseline (59.091 us; speedup 1.0000x reference)
//
#include <hip/hip_runtime.h>

// Problem constants (match reference setup_inputs)
#define K_SIZE 5
#define PAD 2
#define SAMPLE_NUM 15
#define DEPTH_MAX 192.0f

constexpr int B = 2, C = 32, H = 240, W = 320;
constexpr int HW = H * W;
constexpr int BHW = B * HW;                 // 153600
constexpr size_t WS_NEED = (size_t)SAMPLE_NUM * BHW * sizeof(float);  // 9.2 MB

typedef float float4a __attribute__((ext_vector_type(4), aligned(16)));
typedef float float4u __attribute__((ext_vector_type(4), aligned(4)));  // unaligned-ok

// ---------------- Kernel A: pre-weights + softmax, thread = (pixel, sample-slot) ----
// 16 lanes per pixel (s = lane&15) -> softmax via __shfl_xor within the 16-group.
// ws layout TRANSPOSED: wpost[s][pix] so B can load weights as float4 across pixels.
// Stored value = final accumulation weight: softmax prob, or 0 for OOB (zero-pad feat).
__global__ __launch_bounds__(256) void weights_kernel(
    const float* __restrict__ depth,      // [B,1,H,W]
    const float* __restrict__ sn,         // [B,3,H,W]
    const float* __restrict__ guide,      // [B,H,W,25]
    const int*   __restrict__ sample_idx, // [15]
    float* __restrict__ wpost)            // [15][BHW]
{
    const int t   = threadIdx.x;
    const int s   = t & 15;               // sample slot (15 = pad lane)
    const int lp  = t >> 4;               // local pixel
    const int pg  = blockIdx.x * 16 + lp; // global pixel id
    const int b   = pg / HW;
    const int pix = pg - b * HW;
    const int y   = pix / W;
    const int x   = pix - y * W;

    const float* snb = sn + (size_t)b * 3 * HW;
    const float* db  = depth + (size_t)b * HW;

    float prew = 0.0f;     // pre-softmax weight (0 for OOB/invalid-depth/pad lane)
    bool  inb  = false;
    if (s < SAMPLE_NUM) {
        int pp = sample_idx[s];
        int dy = pp / K_SIZE - PAD;
        int dx = pp - (pp / K_SIZE) * K_SIZE - PAD;
        int yy = y + dy, xx = x + dx;
        inb = (yy >= 0) && (yy < H) && (xx >= 0) && (xx < W);
        if (inb) {
            int noff = yy * W + xx;
            float d = db[noff];
            if (d > 0.0f && d < DEPTH_MAX) {
                // center_n per reference: RAW RESHAPE [B,3,H,W] -> (B,H,W,3):
                // contiguous 3 floats at flat offset pix*3 (broadcast across the 16 lanes)
                int o = pix * 3;
                float cn0 = snb[o], cn1 = snb[o + 1], cn2 = snb[o + 2];
                float d0 = snb[noff]          - cn0;
                float d1 = snb[HW + noff]     - cn1;
                float d2 = snb[2 * HW + noff] - cn2;
                float diff = sqrtf(d0 * d0 + d1 * d1 + d2 * d2);
                prew = __expf(-0.5f * diff) * guide[((size_t)b * HW + pix) * 25 + pp];
            }
        }
    }

    // softmax across the 16-lane group (pad lane: prew=0 can't raise max since all >=0,
    // and its exp term is masked out of the sum)
    float m = prew;
    #pragma unroll
    for (int mask = 1; mask < 16; mask <<= 1)
        m = fmaxf(m, __shfl_xor(m, mask, 16));
    float e = (s < SAMPLE_NUM) ? __expf(prew - m) : 0.0f;
    float sum = e;
    #pragma unroll
    for (int mask = 1; mask < 16; mask <<= 1)
        sum += __shfl_xor(sum, mask, 16);

    if (s < SAMPLE_NUM)
        wpost[(size_t)s * BHW + pg] = inb ? (e / sum) : 0.0f;
}

// ---------------- Kernel B: pure gather, thread = (pixel-quad, channel) --------------
constexpr int CHUNKS = BHW / 256;      // 600 chunks of 256 pixels (64 quads)
constexpr int XCHUNK = CHUNKS / 8;     // 75 per XCD

__global__ __launch_bounds__(256) void gather_kernel(
    const float* __restrict__ features,   // [B,C,H,W]
    const int*   __restrict__ sample_idx, // [15]
    const float* __restrict__ wpost,      // [15][BHW]
    float* __restrict__ out,              // [B,C,H,W]
    float* __restrict__ feat_out)         // [B,C,H,W]
{
    // XCD-chunked swizzle: each XCD owns a contiguous pixel span for all channel groups
    int bid   = blockIdx.x;              // 0..4799
    int xcd   = bid & 7;
    int k     = bid >> 3;                // 0..599
    int chunk = xcd * XCHUNK + (k % XCHUNK);
    int g     = k / XCHUNK;              // channel group 0..7

    const int t   = threadIdx.x;
    const int qc  = t & 63;              // local quad (wave = 64 quads x 1 channel)
    const int cs  = t >> 6;              // channel within group
    const int c   = g * 4 + cs;
    const int pg0 = chunk * 256 + qc * 4;  // first pixel of quad (global id)
    const int b   = pg0 / HW;
    const int pix0 = pg0 - b * HW;
    const int y   = pix0 / W;            // quads never cross rows (4 | W)
    const int x0  = pix0 - y * W;

    const float* fb = features + ((size_t)b * C + c) * HW;

    float4a acc = {0.0f, 0.0f, 0.0f, 0.0f};

    #pragma unroll
    for (int s = 0; s < SAMPLE_NUM; ++s) {
        int pp = sample_idx[s];          // wave-uniform -> scalar
        int dy = pp / K_SIZE - PAD;
        int dx = pp - (pp / K_SIZE) * K_SIZE - PAD;
        int yy = y + dy;
        if (yy < 0 || yy >= H) continue;               // weights are 0 there
        float4a w4 = *(const float4a*)(wpost + (size_t)s * BHW + pg0);  // 16B aligned
        const float* frow = fb + yy * W;
        int xx0 = x0 + dx;
        if (xx0 >= 0 && xx0 <= W - 4) {
            float4u f4 = *(const float4u*)(frow + xx0); // 4B-aligned dwordx4
            acc += w4 * f4;
        } else {
            #pragma unroll
            for (int i = 0; i < 4; ++i) {
                int xx = xx0 + i;
                if (xx >= 0 && xx < W) acc[i] += w4[i] * frow[xx];
                // OOB pixels: w4[i]==0 and feature is zero-pad -> contributes 0
            }
        }
    }

    size_t obase = ((size_t)b * C + c) * HW + pix0;
    float4a pf = *(const float4a*)(fb + pix0);          // passthrough (aligned)
    *(float4a*)(out + obase)      = acc;
    *(float4a*)(feat_out + obase) = pf;
}

// ---------------- Fallback (round-3 fused kernel) if ws is too small ----------------
__global__ __launch_bounds__(256) void fused_fallback(
    const float* __restrict__ depth, const float* __restrict__ sn,
    const float* __restrict__ features, const float* __restrict__ guide,
    const int* __restrict__ sample_idx, float* __restrict__ out,
    float* __restrict__ feat_out)
{
    constexpr int PIX_BLOCKS = BHW / 256;
    int pb = blockIdx.x % PIX_BLOCKS;
    int g  = blockIdx.x / PIX_BLOCKS;
    int n  = pb * 256 + threadIdx.x;
    int b = n / HW, pix = n - b * HW, y = pix / W, x = pix - y * W;
    const float* snb = sn + (size_t)b * 3 * HW;
    const float* db  = depth + (size_t)b * HW;
    const float* gb  = guide + ((size_t)b * HW + pix) * 25;
    int o = pix * 3;
    float cn0 = snb[o], cn1 = snb[o + 1], cn2 = snb[o + 2];
    float w[SAMPLE_NUM]; int offs[SAMPLE_NUM]; bool inbv[SAMPLE_NUM];
    float m = 0.0f;
    #pragma unroll
    for (int s = 0; s < SAMPLE_NUM; ++s) {
        int pp = sample_idx[s];
        int dy = pp / K_SIZE - PAD, dx = pp - (pp / K_SIZE) * K_SIZE - PAD;
        int yy = y + dy, xx = x + dx;
        bool inb = (yy >= 0) && (yy < H) && (xx >= 0) && (xx < W);
        inbv[s] = inb;
        int noff = inb ? (yy * W + xx) : pix;
        offs[s] = noff;
        float ww = 0.0f;
        if (inb) {
            float d = db[noff];
            if (d > 0.0f && d < DEPTH_MAX) {
                float d0 = snb[noff] - cn0, d1 = snb[HW + noff] - cn1, d2 = snb[2 * HW + noff] - cn2;
                ww = __expf(-0.5f * sqrtf(d0 * d0 + d1 * d1 + d2 * d2)) * gb[pp];
            }
        }
        w[s] = ww; m = fmaxf(m, ww);
    }
    float sum = 0.0f;
    #pragma unroll
    for (int s = 0; s < SAMPLE_NUM; ++s) { w[s] = __expf(w[s] - m); sum += w[s]; }
    float inv = 1.0f / sum;
    #pragma unroll
    for (int s = 0; s < SAMPLE_NUM; ++s) w[s] = inbv[s] ? (w[s] * inv) : 0.0f;
    const float* fb = features + (size_t)b * C * HW;
    float* ob = out + (size_t)b * C * HW;
    float* fob = feat_out + (size_t)b * C * HW;
    int c0 = g * 8;
    #pragma unroll
    for (int cc = 0; cc < 8; ++cc) {
        const float* fc = fb + (c0 + cc) * HW;
        float acc = 0.0f;
        #pragma unroll
        for (int s = 0; s < SAMPLE_NUM; ++s) acc += w[s] * fc[offs[s]];
        ob[(size_t)(c0 + cc) * HW + pix] = acc;
        fob[(size_t)(c0 + cc) * HW + pix] = fc[pix];
    }
}

extern "C" void kernel_launch(void* const* d_in, const int* in_sizes, int n_in,
                              void* d_out, int out_size, void* d_ws, size_t ws_size,
                              hipStream_t stream) {
    const float* depth      = (const float*)d_in[0];
    const float* sn         = (const float*)d_in[1];
    const float* features   = (const float*)d_in[2];
    const float* guide      = (const float*)d_in[3];
    const int*   sample_idx = (const int*)d_in[4];

    float* out      = (float*)d_out;                      // [B,C,H,W]
    float* feat_out = (float*)d_out + (size_t)B * C * HW; // [B,C,H,W]

    if (ws_size >= WS_NEED) {
        float* wpost = (float*)d_ws;
        weights_kernel<<<BHW / 16, 256, 0, stream>>>(depth, sn, guide, sample_idx, wpost);
        gather_kernel<<<CHUNKS * 8, 256, 0, stream>>>(features, sample_idx, wpost, out, feat_out);
    } else {
        fused_fallback<<<(BHW / 256) * 4, 256, 0, stream>>>(
            depth, sn, features, guide, sample_idx, out, feat_out);
    }
}

// Round 7
// 44.106 us; speedup vs baseline: 1.3398x; 1.3398x over previous
//
#include <hip/hip_runtime.h>

// Problem constants (match reference setup_inputs)
#define K_SIZE 5
#define PAD 2
#define SAMPLE_NUM 15
#define DEPTH_MAX 192.0f

constexpr int B = 2, C = 32, H = 240, W = 320;
constexpr int HW  = H * W;
constexpr int BHW = B * HW;
constexpr int PPB = 64;              // pixels per block (quarter row; never crosses a row)
constexpr int NBLK = BHW / PPB;      // 2400
constexpr int XCHUNK = NBLK / 8;     // 300 contiguous blocks per XCD

typedef float float4a __attribute__((ext_vector_type(4), aligned(16)));
typedef float float4u __attribute__((ext_vector_type(4), aligned(4)));  // 4B-aligned ok

__global__ __launch_bounds__(256) void adaptive_sample_fused(
    const float* __restrict__ depth,      // [B,1,H,W]
    const float* __restrict__ sn,         // [B,3,H,W]
    const float* __restrict__ features,   // [B,C,H,W]
    const float* __restrict__ guide,      // [B,H,W,25]
    const int*   __restrict__ sample_idx, // [15]
    float* __restrict__ out,              // [B,C,H,W]
    float* __restrict__ feat_out)         // [B,C,H,W]
{
    // +4 pad: row stride 272B (16B-aligned for ds_read_b128, 2-way max conflicts)
    __shared__ __align__(16) float w_lds[SAMPLE_NUM][PPB + 4];

    // XCD-chunked swizzle: each XCD owns 300 contiguous blocks (60 image rows)
    int bid = blockIdx.x;
    int blk = (bid & 7) * XCHUNK + (bid >> 3);

    const int t       = threadIdx.x;
    const int base    = blk * PPB;        // first global pixel of block
    const int b       = base / HW;        // block never crosses batch (64 | HW)
    const int pixbase = base - b * HW;    // within-batch pixel base

    const float* snb = sn + (size_t)b * 3 * HW;
    const float* db  = depth + (size_t)b * HW;

    // ---------------- phase 1: weights + softmax -> LDS ----------------
    {
        const int s  = t & 15;            // sample slot (15 = pad lane)
        const int lq = t >> 4;            // 0..15
        #pragma unroll
        for (int kk = 0; kk < 4; ++kk) {
            int lp  = kk * 16 + lq;       // local pixel 0..63
            int pix = pixbase + lp;
            int y = pix / W, x = pix - (pix / W) * W;

            float prew = 0.0f;            // pre-softmax weight
            bool  inb  = false;
            if (s < SAMPLE_NUM) {
                int pp = sample_idx[s];
                int dy = pp / K_SIZE - PAD;
                int dx = pp - (pp / K_SIZE) * K_SIZE - PAD;
                int yy = y + dy, xx = x + dx;
                inb = (yy >= 0) && (yy < H) && (xx >= 0) && (xx < W);
                if (inb) {
                    int noff = yy * W + xx;
                    float d = db[noff];
                    if (d > 0.0f && d < DEPTH_MAX) {
                        // center_n per reference: RAW RESHAPE [B,3,H,W] -> (B,H,W,3)
                        int o = pix * 3;
                        float cn0 = snb[o], cn1 = snb[o + 1], cn2 = snb[o + 2];
                        float d0 = snb[noff]          - cn0;
                        float d1 = snb[HW + noff]     - cn1;
                        float d2 = snb[2 * HW + noff] - cn2;
                        float diff = sqrtf(d0 * d0 + d1 * d1 + d2 * d2);
                        prew = __expf(-0.5f * diff)
                             * guide[((size_t)b * HW + pix) * 25 + pp];
                    }
                }
            }
            // softmax across the 16-lane group (pad lane: prew=0 can't raise max;
            // its exp term is excluded from the sum)
            float m = prew;
            #pragma unroll
            for (int mask = 1; mask < 16; mask <<= 1)
                m = fmaxf(m, __shfl_xor(m, mask, 16));
            float e = (s < SAMPLE_NUM) ? __expf(prew - m) : 0.0f;
            float sum = e;
            #pragma unroll
            for (int mask = 1; mask < 16; mask <<= 1)
                sum += __shfl_xor(sum, mask, 16);
            if (s < SAMPLE_NUM)
                w_lds[s][lp] = inb ? (e / sum) : 0.0f;  // OOB -> accum weight 0 (zero-pad feat)
        }
    }
    __syncthreads();

    // ---------------- phase 2: branch-free vector gather ----------------
    {
        const int q    = t & 15;          // quad within block (16 quads of 4 pixels)
        const int cs   = t >> 4;          // 0..15
        const int p0   = pixbase + q * 4; // within-batch first pixel of quad
        const int y    = p0 / W;
        const int x0   = p0 - y * W;      // quads never cross rows (4 | W, 64 | W-chunks)
        const bool edge = (x0 == 0) || (x0 == W - 4);   // x-clamp shifts the window here

        #pragma unroll
        for (int it = 0; it < 2; ++it) {
            const int c = it * 16 + cs;
            const float* fb = features + ((size_t)b * C + c) * HW;

            float4a acc = {0.0f, 0.0f, 0.0f, 0.0f};
            #pragma unroll
            for (int ss = 0; ss < SAMPLE_NUM; ++ss) {
                int pp = sample_idx[ss];  // wave-uniform -> scalar
                int dy = pp / K_SIZE - PAD;
                int dx = pp - (pp / K_SIZE) * K_SIZE - PAD;
                int yy = min(max(y + dy, 0), H - 1);        // OOB rows: weights are 0
                int xx0 = min(max(x0 + dx, 0), W - 4);      // identity for interior quads
                float4a w4 = *(const float4a*)&w_lds[ss][q * 4];   // ds_read_b128
                float4u f4 = *(const float4u*)(fb + yy * W + xx0); // unaligned dwordx4
                acc += w4 * f4;
            }
            if (edge) {
                // exact per-element recompute: weights are 0 at true-OOB x/y, so
                // clamped addresses are safe and contribute 0.
                float a0 = 0, a1 = 0, a2 = 0, a3 = 0;
                #pragma unroll
                for (int ss = 0; ss < SAMPLE_NUM; ++ss) {
                    int pp = sample_idx[ss];
                    int dy = pp / K_SIZE - PAD;
                    int dx = pp - (pp / K_SIZE) * K_SIZE - PAD;
                    int yy = min(max(y + dy, 0), H - 1);
                    const float* frow = fb + yy * W;
                    int xb = x0 + dx;
                    a0 += w_lds[ss][q * 4 + 0] * frow[min(max(xb + 0, 0), W - 1)];
                    a1 += w_lds[ss][q * 4 + 1] * frow[min(max(xb + 1, 0), W - 1)];
                    a2 += w_lds[ss][q * 4 + 2] * frow[min(max(xb + 2, 0), W - 1)];
                    a3 += w_lds[ss][q * 4 + 3] * frow[min(max(xb + 3, 0), W - 1)];
                }
                acc = float4a{a0, a1, a2, a3};
            }

            size_t obase = ((size_t)b * C + c) * HW + p0;
            float4a pf = *(const float4a*)(fb + p0);     // aligned passthrough
            *(float4a*)(out + obase)      = acc;
            *(float4a*)(feat_out + obase) = pf;
        }
    }
}

extern "C" void kernel_launch(void* const* d_in, const int* in_sizes, int n_in,
                              void* d_out, int out_size, void* d_ws, size_t ws_size,
                              hipStream_t stream) {
    const float* depth      = (const float*)d_in[0];
    const float* sn         = (const float*)d_in[1];
    const float* features   = (const float*)d_in[2];
    const float* guide      = (const float*)d_in[3];
    const int*   sample_idx = (const int*)d_in[4];

    float* out      = (float*)d_out;                      // [B,C,H,W]
    float* feat_out = (float*)d_out + (size_t)B * C * HW; // [B,C,H,W]

    adaptive_sample_fused<<<NBLK, 256, 0, stream>>>(
        depth, sn, features, guide, sample_idx, out, feat_out);
}